// Round 10
// baseline (12473.531 us; speedup 1.0000x reference)
//
#include <hip/hip_runtime.h>
#include <math.h>

// PixelQueryNet v10: lane = pixel, wave = cell, weights via LDS broadcast.
// Per low-res cell (b,i,j): MLP 4->64->64->64->64->3 (leaky 0.01, tanh) on the
// 64 pixels of its 8x8 tile; weights from lr_params[b,c,i,j] (channel stride
// PLANE=4096 floats).
//
// Block = 512 threads = 8 waves = 8 cells (j-group). Lane = pixel. act[64] and
// y[64] fully in registers (all static indices) -> no LDS activation traffic,
// no transpose, no cross-wave exchange. Weights are wave-uniform: staged
// cooperatively into LDS [j][ch] chunks (1024 ch x 8 j, double-buffered,
// 64-line-COALESCED b32 loads: 8j x 4B contiguous runs; sibling block n^8 on
// the same XCD covers the other half of each 64B line -> HBM ideal), consumed
// via same-address ds_read_b128 broadcasts (16 per ci). 13 barriers total.
//
// R4-R8 lesson: the old per-lane float4 staging (stride 16KB) was a 64-line
// GATHER per inst -> ~1000cy service stalls that pinned VALUBusy at ~37%.
// R9 lesson: avoid register spills (no big temps; y-init from bias).

static constexpr int PLANE = 4096;
static constexpr int NPAR  = 12995;
static constexpr int CHROW = 1032;   // chunk row stride (words; mod 32 = 8)
static constexpr int SMROW = 712;    // smalls row stride (words; mod 32 = 8)

__device__ __forceinline__ float leaky(float v) { return fmaxf(v, 0.01f * v); }

__global__ __launch_bounds__(512, 2) void pqn(const float* __restrict__ lr,
                                              float* __restrict__ out) {
  __shared__ alignas(16) float CH[2][8 * CHROW];  // 66048 B  weight chunks
  __shared__ alignas(16) float SM[8 * SMROW];     // 22784 B  bias/L0/L4 region

  const int tid  = threadIdx.x;
  const int w    = tid >> 6;          // wave id = cell within j-group
  const int lane = tid & 63;          // pixel
  const int dx = lane & 7, dy = lane >> 3;

  const int sch = tid >> 3;           // staging channel-offset 0..63
  const int sj  = tid & 7;            // staging j 0..7

  // ---- pair swizzle: blocks n, n+8 (same XCD) take adjacent j-groups so each
  // 64B weight line is fully consumed within one XCD (proven FETCH-ideal).
  const int n = blockIdx.x;
  const int e = (n >> 3) & 1;
  const int P = (n & 7) | ((n >> 4) << 3);   // 0..511
  const int jg = ((P & 3) << 1) | e;         // 0..7
  const int i  = (P >> 2) & 63;
  const int b  = (P >> 8) & 1;
  const int col0 = i * 64 + jg * 8;

  const float* __restrict__ gbase = lr + (size_t)b * NPAR * PLANE + col0;

  // ---- prologue staging: smalls (L0 + hidden biases + L4) and chunk 0.
  // smalls region offset -> channel map:
  //   [0,384)   : c = ofs              (L0 bias+weights, l0 bias 320..383)
  //   [384,448) : c = 4096 + ofs       (l1 bias 4480..4543)
  //   [448,512) : c = 8192 + ofs       (l2 bias 8640..8703)
  //   [512,515) : c = 12288 + ofs      (L4 bias)
  //   [520,712) : o=(ofs-520)>>6, ci=(ofs-520)&63, c = 12803+ci*3+o (L4 w^T)
  {
    float sm[12], st[16];
#pragma unroll
    for (int it = 0; it < 12; ++it) {
      const int ofs = sch + 64 * it;
      int c = 0;
      if (ofs < 384) c = ofs;
      else if (ofs < 448) c = 4096 + ofs;
      else if (ofs < 512) c = 8192 + ofs;
      else if (ofs < 515) c = 12288 + ofs;
      else if (ofs >= 520 && ofs < 712) {
        const int u = ofs - 520;
        c = 12803 + (u & 63) * 3 + (u >> 6);
      }
      sm[it] = (ofs < 712) ? gbase[(size_t)c * PLANE + sj] : 0.f;
    }
#pragma unroll
    for (int it = 0; it < 16; ++it)
      st[it] = gbase[(size_t)(384 + sch + 64 * it) * PLANE + sj];
#pragma unroll
    for (int it = 0; it < 12; ++it) {
      const int ofs = sch + 64 * it;
      if (ofs < 712) SM[sj * SMROW + ofs] = sm[it];
    }
#pragma unroll
    for (int it = 0; it < 16; ++it)
      CH[0][sj * CHROW + sch + 64 * it] = st[it];
  }
  asm volatile("s_waitcnt lgkmcnt(0)" ::: "memory");
  __builtin_amdgcn_s_barrier();

  // ---- PE features for this lane's pixel
  float f0, f1, f2, f3;
  {
    float s, c;
    sincosf(0.78539816339744830962f * dx, &s, &c); f0 = c; f1 = s;
    sincosf(0.78539816339744830962f * dy, &s, &c); f2 = c; f3 = s;
  }

  const float* __restrict__ smw = &SM[w * SMROW];  // wave-uniform -> broadcast

  // ---- L0: act[co] = leaky(b + f.w)
  float act[64], y[64];
#pragma unroll
  for (int q = 0; q < 16; ++q) {
    const float4 bq = *(const float4*)&smw[q * 4];
    const float4 w0 = *(const float4*)&smw[64 + q * 4];
    const float4 w1 = *(const float4*)&smw[128 + q * 4];
    const float4 w2 = *(const float4*)&smw[192 + q * 4];
    const float4 w3 = *(const float4*)&smw[256 + q * 4];
#pragma unroll
    for (int m = 0; m < 4; ++m) {
      float v = ((const float*)&bq)[m];
      v = fmaf(f0, ((const float*)&w0)[m], v);
      v = fmaf(f1, ((const float*)&w1)[m], v);
      v = fmaf(f2, ((const float*)&w2)[m], v);
      v = fmaf(f3, ((const float*)&w3)[m], v);
      act[q * 4 + m] = leaky(v);
    }
  }

  // ---- hidden layers: 4 chunks of 16 ci each, double-buffered in CH.
  float st[16];
  int cbase = 384;
  for (int l = 0; l < 3; ++l) {
    // y init = layer bias (broadcast from smalls)
#pragma unroll
    for (int q = 0; q < 16; ++q) {
      const float4 bq = *(const float4*)&smw[320 + l * 64 + q * 4];
      y[q * 4 + 0] = bq.x; y[q * 4 + 1] = bq.y;
      y[q * 4 + 2] = bq.z; y[q * 4 + 3] = bq.w;
    }

#define CHUNK(K)                                                          \
    {                                                                     \
      asm volatile("s_waitcnt lgkmcnt(0)" ::: "memory");                  \
      __builtin_amdgcn_s_barrier();                                       \
      const bool stg = (l < 2) || ((K) < 3);                              \
      const int cn = cbase + ((K) < 3 ? ((K) + 1) * 1024 : 4160);         \
      if (stg) {                                                          \
        _Pragma("unroll")                                                 \
        for (int it = 0; it < 16; ++it)                                   \
          st[it] = gbase[(size_t)(cn + sch + 64 * it) * PLANE + sj];      \
      }                                                                   \
      const float* bb = &CH[(K) & 1][w * CHROW];                          \
      _Pragma("unroll")                                                   \
      for (int cc = 0; cc < 16; ++cc) {                                   \
        const float a = act[(K) * 16 + cc];                               \
        _Pragma("unroll")                                                 \
        for (int q = 0; q < 16; ++q) {                                    \
          const float4 wq = *(const float4*)&bb[cc * 64 + q * 4];         \
          y[q * 4 + 0] = fmaf(a, wq.x, y[q * 4 + 0]);                     \
          y[q * 4 + 1] = fmaf(a, wq.y, y[q * 4 + 1]);                     \
          y[q * 4 + 2] = fmaf(a, wq.z, y[q * 4 + 2]);                     \
          y[q * 4 + 3] = fmaf(a, wq.w, y[q * 4 + 3]);                     \
        }                                                                 \
      }                                                                   \
      if (stg) {                                                          \
        float* wdst = &CH[((K) + 1) & 1][sj * CHROW];                     \
        _Pragma("unroll")                                                 \
        for (int it = 0; it < 16; ++it)                                   \
          wdst[sch + 64 * it] = st[it];                                   \
      }                                                                   \
    }

    CHUNK(0)
    CHUNK(1)
    CHUNK(2)
    CHUNK(3)
#undef CHUNK

    // layer end: act = leaky(y)
#pragma unroll
    for (int m = 0; m < 64; ++m) act[m] = leaky(y[m]);
    cbase += 4160;
  }

  // ---- L4 (64 -> 3) + tanh; w4 transposed in smalls at 520 + o*64 + ci
  float p0 = smw[512], p1 = smw[513], p2 = smw[514];
#pragma unroll
  for (int cg = 0; cg < 16; ++cg) {
    const float4 r0 = *(const float4*)&smw[520 + cg * 4];
    const float4 r1 = *(const float4*)&smw[520 + 64 + cg * 4];
    const float4 r2 = *(const float4*)&smw[520 + 128 + cg * 4];
#pragma unroll
    for (int u = 0; u < 4; ++u) {
      const float a = act[cg * 4 + u];
      p0 = fmaf(a, ((const float*)&r0)[u], p0);
      p1 = fmaf(a, ((const float*)&r1)[u], p1);
      p2 = fmaf(a, ((const float*)&r2)[u], p2);
    }
  }

  float* op = out + (size_t)b * 786432 +
              (size_t)(i * 8 + dy) * 512 + (size_t)((jg * 8 + w) * 8 + dx);
  op[0]      = tanhf(p0);
  op[262144] = tanhf(p1);
  op[524288] = tanhf(p2);
}

extern "C" void kernel_launch(void* const* d_in, const int* in_sizes, int n_in,
                              void* d_out, int out_size, void* d_ws, size_t ws_size,
                              hipStream_t stream) {
  (void)in_sizes; (void)n_in; (void)d_ws; (void)ws_size; (void)out_size;
  const float* lr = (const float*)d_in[1];  // d_in[0] = highres (unused by the math)
  float* out = (float*)d_out;
  hipLaunchKernelGGL(pqn, dim3(1024), dim3(512), 0, stream, lr, out);
}